// Round 1
// 323.517 us; speedup vs baseline: 1.0641x; 1.0641x over previous
//
#include <hip/hip_runtime.h>

typedef unsigned short u16;
typedef unsigned int u32;
typedef __attribute__((ext_vector_type(8))) short short8;
typedef __attribute__((ext_vector_type(4))) float f32x4;

// async global->LDS, 16B per lane; LDS dst = wave-uniform base + lane*16
#define ASYNC_CP16(gsrc, ldst) \
  __builtin_amdgcn_global_load_lds((__attribute__((address_space(1))) void*)(gsrc), \
                                   (__attribute__((address_space(3))) void*)(ldst), 16, 0, 0)

static __device__ __forceinline__ u16 f2bf(float f) {
  u32 u = __builtin_bit_cast(u32, f);
  u = u + 0x7fffu + ((u >> 16) & 1u);   // RNE
  return (u16)(u >> 16);
}
static __device__ __forceinline__ u32 pk2(float a, float b) {
  return (u32)f2bf(a) | ((u32)f2bf(b) << 16);
}
// fast pack: round-half-up then v_perm_b32 grabs the two high halves (3 VALU ops)
static __device__ __forceinline__ u32 pk2r(float a, float b) {
  u32 ua = __builtin_bit_cast(u32, a) + 0x8000u;
  u32 ub = __builtin_bit_cast(u32, b) + 0x8000u;
  return __builtin_amdgcn_perm(ub, ua, 0x07060302);  // res = [ua.b2,ua.b3,ub.b2,ub.b3]
}

// ---------------------------------------------------------------------------
// Kernel 0: fp32 -> bf16 conversion into ws.
// ---------------------------------------------------------------------------
__global__ __launch_bounds__(256) void convert_all(
    const float* __restrict__ xq, const float* __restrict__ xkv,
    const float* __restrict__ wq, const float* __restrict__ wk,
    const float* __restrict__ wv, const float* __restrict__ wo,
    u16* __restrict__ dst)
{
  long i = ((long)blockIdx.x * 256 + threadIdx.x) * 4;
  const float* s; long o;
  if      (i < 8388608)  { s = xq;  o = i; }
  else if (i < 16777216) { s = xkv; o = i - 8388608; }
  else if (i < 17825792) { s = wq;  o = i - 16777216; }
  else if (i < 18874368) { s = wk;  o = i - 17825792; }
  else if (i < 19922944) { s = wv;  o = i - 18874368; }
  else                   { s = wo;  o = i - 19922944; }
  float4 v = *(const float4*)(s + o);
  uint2 pkv; pkv.x = pk2(v.x, v.y); pkv.y = pk2(v.z, v.w);
  *(uint2*)(dst + i) = pkv;
}

// ---------------------------------------------------------------------------
// GEMM: C[m][n] = sum_k A[m][k] * W[n][k] + bias[n]   (m97 structure)
// EPI=0: QKV projections (z selects):
//   z=0: Q * (0.125*log2e), layout [bh][n][64]
//   z=1: K chunked  [bh][kt=n/128][dblk=d/8][key=n%128][8]   (8192 u16/tile)
//   z=2: V^T chunked [bh][kt][keyblk=(n%128)/8][d][8]        (8192 u16/tile)
// EPI=1: output projection; writes fp32 [tok][1024].
// ---------------------------------------------------------------------------
template<int EPI>
__global__ __launch_bounds__(256)
void gemm_k(const u16* __restrict__ Axq, const u16* __restrict__ Axkv,
            const u16* __restrict__ W0, const u16* __restrict__ W1, const u16* __restrict__ W2,
            const float* __restrict__ b0, const float* __restrict__ b1, const float* __restrict__ b2,
            u16* __restrict__ Qo, u16* __restrict__ Ko, u16* __restrict__ Vo,
            float* __restrict__ Fo)
{
  __shared__ u16 lsa[128*32];
  __shared__ u16 lsb[128*32];
  const int tid = threadIdx.x;
  const int w = tid >> 6, lane = tid & 63;
  const int wr = w >> 1, wc = w & 1;
  const int bm = blockIdx.x, bn = blockIdx.y, z = blockIdx.z;
  const int l15 = lane & 15, l4 = lane >> 4;

  const u16* A; const u16* W; const float* bias;
  if (EPI == 0) {
    A    = (z == 0) ? Axq : Axkv;
    W    = (z == 0) ? W0 : (z == 1) ? W1 : W2;
    bias = (z == 0) ? b0 : (z == 1) ? b1 : b2;
  } else {
    A = Axq; W = W0; bias = b0;
  }
  const u16* Ag = A + (long)bm*128*1024;
  const u16* Wg = W + (long)bn*128*1024;

  f32x4 acc[4][4];
#pragma unroll
  for (int i = 0; i < 4; ++i)
#pragma unroll
    for (int j = 0; j < 4; ++j)
      acc[i][j] = (f32x4){0.f,0.f,0.f,0.f};

  for (int k0 = 0; k0 < 1024; k0 += 32) {
    __syncthreads();
#pragma unroll
    for (int c = 0; c < 2; ++c) {
      int tp = c*256 + tid;
      int row = tp >> 2, col = (tp & 3) * 8;
      ASYNC_CP16(Ag + (long)row*1024 + k0 + col, &lsa[tp*8]);
      ASYNC_CP16(Wg + (long)row*1024 + k0 + col, &lsb[tp*8]);
    }
    __syncthreads();
    short8 af[4], bfr[4];
#pragma unroll
    for (int i = 0; i < 4; ++i)
      af[i] = *(const short8*)&lsa[(wr*64 + i*16 + l15)*32 + l4*8];
#pragma unroll
    for (int j = 0; j < 4; ++j)
      bfr[j] = *(const short8*)&lsb[(wc*64 + j*16 + l15)*32 + l4*8];
#pragma unroll
    for (int i = 0; i < 4; ++i)
#pragma unroll
      for (int j = 0; j < 4; ++j)
        acc[i][j] = __builtin_amdgcn_mfma_f32_16x16x32_bf16(af[i], bfr[j], acc[i][j], 0, 0, 0);
  }

#pragma unroll
  for (int j = 0; j < 4; ++j) {
    const int colg = bn*128 + wc*64 + j*16 + l15;
    const float bb = bias[colg];
#pragma unroll
    for (int i = 0; i < 4; ++i) {
      const int rowg = bm*128 + wr*64 + i*16 + l4*4;
      if (EPI == 1) {
#pragma unroll
        for (int r = 0; r < 4; ++r)
          Fo[(long)(rowg + r)*1024 + colg] = acc[i][j][r] + bb;
      } else {
        const int b  = rowg >> 11, n0 = rowg & 2047;
        const int h  = colg >> 6,  c  = colg & 63;
        const int bh = b*16 + h;
        const long hb = (long)bh*131072 + (long)(n0 >> 7)*8192;  // 8192 u16 per 128-key tile
        if (z == 0) {
          // scale = 0.125 * log2(e): softmax done in exp2 domain
#pragma unroll
          for (int r = 0; r < 4; ++r)
            Qo[((long)bh*2048 + n0 + r)*64 + c] = f2bf((acc[i][j][r] + bb) * 0.18033688f);
        } else if (z == 1) {
          const long base = hb + (long)(c >> 3)*1024 + (n0 & 127)*8 + (c & 7);
#pragma unroll
          for (int r = 0; r < 4; ++r)
            Ko[base + r*8] = f2bf(acc[i][j][r] + bb);
        } else {
          // n0 % 4 == 0 so rows n0..n0+3 stay inside one 8-key block
          const long base = hb + (long)((n0 & 127) >> 3)*512 + (long)c*8 + (n0 & 7);
          uint2 pkv;
          pkv.x = pk2(acc[i][j][0] + bb, acc[i][j][1] + bb);
          pkv.y = pk2(acc[i][j][2] + bb, acc[i][j][3] + bb);
          *(uint2*)(Vo + base) = pkv;
        }
      }
    }
  }
}

// ---------------------------------------------------------------------------
// Flash attention, causal, S^T orientation, NO online max (scores bounded in
// exp2 domain; masked -> -1e30 -> exp2 -> 0).
// v2: 8 waves / 128 queries per block (halves K/V tile loads + iterations),
// double-buffered K/V tiles with counted vmcnt(4): next tile's
// global_load_lds stay in flight across a raw s_barrier while the current
// tile computes (T3+T4). LDS = 80 KB -> 2 blk/CU = 16 waves/CU.
// Grid (16, 64), heavy (long-ktmax) blocks first.
// ---------------------------------------------------------------------------
__global__ __launch_bounds__(512, 4)
void attn_k(const u16* __restrict__ Q, const u16* __restrict__ K,
            const u16* __restrict__ V, u16* __restrict__ AO)
{
  __shared__ u16 lk[2][8192];     // K tile dbuf [dblk 8][key 128][8]
  __shared__ u16 lv[2][8192];     // V tile dbuf [keyblk 16][d 64][8]
  __shared__ u16 lp[8][1024];     // per-wave P half: [q 16][key 64], chunk^q&7 swizzle
  const int tid = threadIdx.x;
  const int w = tid >> 6, lane = tid & 63;
  const int l15 = lane & 15, l4 = lane >> 4;
  const int qt = (gridDim.x - 1) - blockIdx.x;   // heavy blocks first
  const int bh = blockIdx.y;
  const int q0 = qt*128;
  const int qg = q0 + w*16 + l15;           // this lane's query row
  const u16* Qh = Q + (long)bh*131072;
  const u16* Kh = K + (long)bh*131072;
  const u16* Vh = V + (long)bh*131072;

  short8 qf[2];
#pragma unroll
  for (int ks = 0; ks < 2; ++ks)
    qf[ks] = *(const short8*)&Qh[(long)qg*64 + ks*32 + l4*8];

  f32x4 o[4];
#pragma unroll
  for (int nt = 0; nt < 4; ++nt) o[nt] = (f32x4){0.f,0.f,0.f,0.f};
  float rsum = 0.f;

  u16* pw = &lp[w][0];
  const int swz_q = (l15 & 7);
  const int ktmax = qt;                     // diagonal tile index (q0 = qt*128)

  // prologue: stage tile 0 into buf 0 (4 cp16 per thread: K,V,K,V)
#pragma unroll
  for (int c = 0; c < 2; ++c) {
    int tp = c*512 + tid;
    ASYNC_CP16(Kh + tp*8, &lk[0][tp*8]);
    ASYNC_CP16(Vh + tp*8, &lv[0][tp*8]);
  }

  for (int kt = 0; kt <= ktmax; ++kt) {
    const int cur = kt & 1;
    // issue next tile's loads into the other buffer (freed by last iter's
    // end-barrier), then wait only for the CURRENT tile's 4 cps: the 4
    // newest ops are the just-issued prefetch -> vmcnt(4) leaves them in
    // flight across the barrier.
    if (kt < ktmax) {
      const long off = (long)(kt + 1)*8192;
#pragma unroll
      for (int c = 0; c < 2; ++c) {
        int tp = c*512 + tid;
        ASYNC_CP16(Kh + off + tp*8, &lk[cur^1][tp*8]);
        ASYNC_CP16(Vh + off + tp*8, &lv[cur^1][tp*8]);
      }
      asm volatile("s_waitcnt vmcnt(4)" ::: "memory");
    } else {
      asm volatile("s_waitcnt vmcnt(0)" ::: "memory");
    }
    __builtin_amdgcn_s_barrier();

    const u16* lkc = &lk[cur][0];
    const u16* lvc = &lv[cur][0];

    // S^T = K . Q^T : 16 MFMA, conflict-free b128 K-frag reads
    f32x4 s[8];
#pragma unroll
    for (int nt = 0; nt < 8; ++nt) s[nt] = (f32x4){0.f,0.f,0.f,0.f};
#pragma unroll
    for (int ks = 0; ks < 2; ++ks)
#pragma unroll
      for (int nt = 0; nt < 8; ++nt) {
        short8 kf = *(const short8*)&lkc[(ks*4 + l4)*1024 + (nt*16 + l15)*8];
        s[nt] = __builtin_amdgcn_mfma_f32_16x16x32_bf16(kf, qf[ks], s[nt], 0, 0, 0);
      }

    // causal mask (diagonal tile only); key = kt*128 + nt*16 + l4*4 + r
    if (kt == ktmax) {
      const int kb = kt*128 + l4*4;
#pragma unroll
      for (int nt = 0; nt < 8; ++nt)
#pragma unroll
        for (int r = 0; r < 4; ++r)
          if (kb + nt*16 + r > qg) s[nt][r] = -1e30f;
    }

    // p = exp2(s); accumulate l per lane (linear -> reduce at end); pack pairs
    u32 pk[8][2];
#pragma unroll
    for (int nt = 0; nt < 8; ++nt) {
      float p0 = __builtin_amdgcn_exp2f(s[nt][0]);
      float p1 = __builtin_amdgcn_exp2f(s[nt][1]);
      float p2 = __builtin_amdgcn_exp2f(s[nt][2]);
      float p3 = __builtin_amdgcn_exp2f(s[nt][3]);
      rsum += (p0 + p1) + (p2 + p3);
      pk[nt][0] = pk2r(p0, p1);
      pk[nt][1] = pk2r(p2, p3);
    }

    // PV in two 64-key halves through the swizzled per-wave buffer
#pragma unroll
    for (int h = 0; h < 2; ++h) {
#pragma unroll
      for (int ntl = 0; ntl < 4; ++ntl) {
        const int chunk = ntl*2 + (l4 >> 1);          // (local key)/8
        const int swz = chunk ^ swz_q;
        uint2 pr; pr.x = pk[4*h + ntl][0]; pr.y = pk[4*h + ntl][1];
        *(uint2*)&pw[l15*64 + swz*8 + (l4 & 1)*4] = pr;
      }
#pragma unroll
      for (int ksl = 0; ksl < 2; ++ksl) {
        const int swz = (ksl*4 + l4) ^ swz_q;
        short8 pf = *(const short8*)&pw[l15*64 + swz*8];
        const int ksg = h*2 + ksl;
#pragma unroll
        for (int nt = 0; nt < 4; ++nt) {
          short8 vf = *(const short8*)&lvc[(ksg*4 + l4)*512 + (nt*16 + l15)*8];
          o[nt] = __builtin_amdgcn_mfma_f32_16x16x32_bf16(vf, pf, o[nt], 0, 0, 0);
        }
      }
    }

    // pin all LDS reads of buf[cur] before the end barrier; next iteration's
    // prefetch overwrites it.
    asm volatile("" ::: "memory");
    __builtin_amdgcn_s_barrier();
  }

  // final l reduction across the 4 key-owner lane groups (xor 16, 32)
  rsum += __shfl_xor(rsum, 16, 64);
  rsum += __shfl_xor(rsum, 32, 64);

  // epilogue: normalize, write bf16 [tok][1024] (merged heads), b64 stores
  const int b = bh >> 4, h = bh & 15;
  const float inv = 1.0f / rsum;
  const long tok = (long)b*2048 + qg;
#pragma unroll
  for (int nt = 0; nt < 4; ++nt) {
    uint2 pkv;
    pkv.x = pk2(o[nt][0]*inv, o[nt][1]*inv);
    pkv.y = pk2(o[nt][2]*inv, o[nt][3]*inv);
    *(uint2*)&AO[tok*1024 + h*64 + nt*16 + l4*4] = pkv;
  }
}

// ---------------------------------------------------------------------------
extern "C" void kernel_launch(void* const* d_in, const int* in_sizes, int n_in,
                              void* d_out, int out_size, void* d_ws, size_t ws_size,
                              hipStream_t stream)
{
  const float* xq  = (const float*)d_in[0];
  const float* xkv = (const float*)d_in[1];
  const float* Wq  = (const float*)d_in[2];
  const float* bq  = (const float*)d_in[3];
  const float* Wk  = (const float*)d_in[4];
  const float* bk  = (const float*)d_in[5];
  const float* Wv  = (const float*)d_in[6];
  const float* bv  = (const float*)d_in[7];
  const float* Wo  = (const float*)d_in[8];
  const float* bo  = (const float*)d_in[9];

  u16* ws    = (u16*)d_ws;
  u16* xq_b  = ws;                    // 8M bf16
  u16* xkv_b = xq_b  + (1l<<23);      // 8M
  u16* wq_b  = xkv_b + (1l<<23);      // 1M
  u16* wk_b  = wq_b  + (1l<<20);
  u16* wv_b  = wk_b  + (1l<<20);
  u16* wo_b  = wv_b  + (1l<<20);
  u16* Qb    = wo_b  + (1l<<20);      // 8M, [bh][n][64], scaled 0.125*log2e
  u16* Kb    = Qb    + (1l<<23);      // 8M, [bh][kt][dblk][key][8]
  u16* Vb    = Kb    + (1l<<23);      // 8M, [bh][kt][keyblk][d][8]
  u16* Ab    = Vb    + (1l<<23);      // 8M, [tok][1024]

  convert_all<<<20480, 256, 0, stream>>>(xq, xkv, Wq, Wk, Wv, Wo, ws);
  gemm_k<0><<<dim3(64,8,3), 256, 0, stream>>>(xq_b, xkv_b, wq_b, wk_b, wv_b,
                                              bq, bk, bv, Qb, Kb, Vb, nullptr);
  attn_k<<<dim3(16,64), 512, 0, stream>>>(Qb, Kb, Vb, Ab);
  gemm_k<1><<<dim3(64,8,1), 256, 0, stream>>>(Ab, nullptr, wo_b, nullptr, nullptr,
                                              bo, nullptr, nullptr,
                                              nullptr, nullptr, nullptr,
                                              (float*)d_out);
}

// Round 2
// 305.659 us; speedup vs baseline: 1.1263x; 1.0584x over previous
//
#include <hip/hip_runtime.h>

typedef unsigned short u16;
typedef unsigned int u32;
typedef __attribute__((ext_vector_type(8))) short short8;
typedef __attribute__((ext_vector_type(4))) float f32x4;
typedef __attribute__((ext_vector_type(16))) float f32x16;
typedef __attribute__((ext_vector_type(4))) unsigned u32x4;

// async global->LDS, 16B per lane; LDS dst = wave-uniform base + lane*16
#define ASYNC_CP16(gsrc, ldst) \
  __builtin_amdgcn_global_load_lds((__attribute__((address_space(1))) void*)(gsrc), \
                                   (__attribute__((address_space(3))) void*)(ldst), 16, 0, 0)

static __device__ __forceinline__ u16 f2bf(float f) {
  u32 u = __builtin_bit_cast(u32, f);
  u = u + 0x7fffu + ((u >> 16) & 1u);   // RNE
  return (u16)(u >> 16);
}
static __device__ __forceinline__ u32 pk2(float a, float b) {
  return (u32)f2bf(a) | ((u32)f2bf(b) << 16);
}
// single-instruction packed f32->2xbf16 (RNE)
static __device__ __forceinline__ u32 cvtpk(float lo, float hi) {
  u32 r;
  asm("v_cvt_pk_bf16_f32 %0, %1, %2" : "=v"(r) : "v"(lo), "v"(hi));
  return r;
}
// swap upper 32 lanes of a with lower 32 lanes of b
static __device__ __forceinline__ void plswap(u32 &a, u32 &b) {
  asm("v_permlane32_swap_b32 %0, %1" : "+v"(a), "+v"(b));
}

// ---------------------------------------------------------------------------
// Kernel 0: fp32 -> bf16 conversion into ws.
// ---------------------------------------------------------------------------
__global__ __launch_bounds__(256) void convert_all(
    const float* __restrict__ xq, const float* __restrict__ xkv,
    const float* __restrict__ wq, const float* __restrict__ wk,
    const float* __restrict__ wv, const float* __restrict__ wo,
    u16* __restrict__ dst)
{
  long i = ((long)blockIdx.x * 256 + threadIdx.x) * 4;
  const float* s; long o;
  if      (i < 8388608)  { s = xq;  o = i; }
  else if (i < 16777216) { s = xkv; o = i - 8388608; }
  else if (i < 17825792) { s = wq;  o = i - 16777216; }
  else if (i < 18874368) { s = wk;  o = i - 17825792; }
  else if (i < 19922944) { s = wv;  o = i - 18874368; }
  else                   { s = wo;  o = i - 19922944; }
  float4 v = *(const float4*)(s + o);
  uint2 pkv; pkv.x = pk2(v.x, v.y); pkv.y = pk2(v.z, v.w);
  *(uint2*)(dst + i) = pkv;
}

// ---------------------------------------------------------------------------
// GEMM: C[m][n] = sum_k A[m][k] * W[n][k] + bias[n]   (m97 structure)
// EPI=0: QKV projections (z selects):
//   z=0: Q * (0.125*log2e), layout [bh][n][64]
//   z=1: K chunked  [bh][kt=n/128][dblk=d/8][key=n%128][8]   (8192 u16/tile)
//   z=2: V^T chunked [bh][kt][keyblk=(n%128)/8][d][8]        (8192 u16/tile)
// EPI=1: output projection; writes fp32 [tok][1024].
// ---------------------------------------------------------------------------
template<int EPI>
__global__ __launch_bounds__(256)
void gemm_k(const u16* __restrict__ Axq, const u16* __restrict__ Axkv,
            const u16* __restrict__ W0, const u16* __restrict__ W1, const u16* __restrict__ W2,
            const float* __restrict__ b0, const float* __restrict__ b1, const float* __restrict__ b2,
            u16* __restrict__ Qo, u16* __restrict__ Ko, u16* __restrict__ Vo,
            float* __restrict__ Fo)
{
  __shared__ u16 lsa[128*32];
  __shared__ u16 lsb[128*32];
  const int tid = threadIdx.x;
  const int w = tid >> 6, lane = tid & 63;
  const int wr = w >> 1, wc = w & 1;
  const int bm = blockIdx.x, bn = blockIdx.y, z = blockIdx.z;
  const int l15 = lane & 15, l4 = lane >> 4;

  const u16* A; const u16* W; const float* bias;
  if (EPI == 0) {
    A    = (z == 0) ? Axq : Axkv;
    W    = (z == 0) ? W0 : (z == 1) ? W1 : W2;
    bias = (z == 0) ? b0 : (z == 1) ? b1 : b2;
  } else {
    A = Axq; W = W0; bias = b0;
  }
  const u16* Ag = A + (long)bm*128*1024;
  const u16* Wg = W + (long)bn*128*1024;

  f32x4 acc[4][4];
#pragma unroll
  for (int i = 0; i < 4; ++i)
#pragma unroll
    for (int j = 0; j < 4; ++j)
      acc[i][j] = (f32x4){0.f,0.f,0.f,0.f};

  for (int k0 = 0; k0 < 1024; k0 += 32) {
    __syncthreads();
#pragma unroll
    for (int c = 0; c < 2; ++c) {
      int tp = c*256 + tid;
      int row = tp >> 2, col = (tp & 3) * 8;
      ASYNC_CP16(Ag + (long)row*1024 + k0 + col, &lsa[tp*8]);
      ASYNC_CP16(Wg + (long)row*1024 + k0 + col, &lsb[tp*8]);
    }
    __syncthreads();
    short8 af[4], bfr[4];
#pragma unroll
    for (int i = 0; i < 4; ++i)
      af[i] = *(const short8*)&lsa[(wr*64 + i*16 + l15)*32 + l4*8];
#pragma unroll
    for (int j = 0; j < 4; ++j)
      bfr[j] = *(const short8*)&lsb[(wc*64 + j*16 + l15)*32 + l4*8];
#pragma unroll
    for (int i = 0; i < 4; ++i)
#pragma unroll
      for (int j = 0; j < 4; ++j)
        acc[i][j] = __builtin_amdgcn_mfma_f32_16x16x32_bf16(af[i], bfr[j], acc[i][j], 0, 0, 0);
  }

#pragma unroll
  for (int j = 0; j < 4; ++j) {
    const int colg = bn*128 + wc*64 + j*16 + l15;
    const float bb = bias[colg];
#pragma unroll
    for (int i = 0; i < 4; ++i) {
      const int rowg = bm*128 + wr*64 + i*16 + l4*4;
      if (EPI == 1) {
#pragma unroll
        for (int r = 0; r < 4; ++r)
          Fo[(long)(rowg + r)*1024 + colg] = acc[i][j][r] + bb;
      } else {
        const int b  = rowg >> 11, n0 = rowg & 2047;
        const int h  = colg >> 6,  c  = colg & 63;
        const int bh = b*16 + h;
        const long hb = (long)bh*131072 + (long)(n0 >> 7)*8192;  // 8192 u16 per 128-key tile
        if (z == 0) {
          // scale = 0.125 * log2(e): softmax done in exp2 domain
#pragma unroll
          for (int r = 0; r < 4; ++r)
            Qo[((long)bh*2048 + n0 + r)*64 + c] = f2bf((acc[i][j][r] + bb) * 0.18033688f);
        } else if (z == 1) {
          const long base = hb + (long)(c >> 3)*1024 + (n0 & 127)*8 + (c & 7);
#pragma unroll
          for (int r = 0; r < 4; ++r)
            Ko[base + r*8] = f2bf(acc[i][j][r] + bb);
        } else {
          // n0 % 4 == 0 so rows n0..n0+3 stay inside one 8-key block
          const long base = hb + (long)((n0 & 127) >> 3)*512 + (long)c*8 + (n0 & 7);
          uint2 pkv;
          pkv.x = pk2(acc[i][j][0] + bb, acc[i][j][1] + bb);
          pkv.y = pk2(acc[i][j][2] + bb, acc[i][j][3] + bb);
          *(uint2*)(Vo + base) = pkv;
        }
      }
    }
  }
}

// ---------------------------------------------------------------------------
// Flash attention v3: 32x32x16 MFMA core (2x LDS arithmetic intensity).
// 8 waves: wave w handles queries q0 + (w&3)*32 .. +31 against key-half
// (w>>2)*64 .. +63 of each 128-key tile. Per wave-iter: 8 QK MFMA + 8 PV
// MFMA, 16 KB LDS fragment reads (vs 40 KB in the 16x16 version).
// P stays in-register: cvt_pk_bf16 + v_permlane32_swap assemble the PV
// B-fragments (T12). Partial O/l of the two key-halves are combined once in
// the epilogue through LDS (reusing the K buffer). K/V double-buffered with
// counted vmcnt(4) across raw barriers. LDS = 64 KB -> 2 blk/CU.
// Causal, no online max (exp2-domain scores bounded; masked -> -1e30 -> 0).
// ---------------------------------------------------------------------------
__global__ __launch_bounds__(512, 4)
void attn_k(const u16* __restrict__ Q, const u16* __restrict__ K,
            const u16* __restrict__ V, u16* __restrict__ AO)
{
  __shared__ u16 lk[2][8192];     // K tile dbuf [dblk 8][key 128][8]
  __shared__ u16 lv[2][8192];     // V tile dbuf [keyblk 16][d 64][8]
  const int tid = threadIdx.x;
  const int w = tid >> 6, lane = tid & 63;
  const int l31 = lane & 31, l5 = lane >> 5;
  const int wq = w & 3, hh = w >> 2;
  const int qt = (gridDim.x - 1) - blockIdx.x;   // heavy blocks first
  const int bh = blockIdx.y;
  const int q0 = qt*128;
  const int qg = q0 + wq*32 + l31;               // this lane's query row
  const u16* Qh = Q + (long)bh*131072;
  const u16* Kh = K + (long)bh*131072;
  const u16* Vh = V + (long)bh*131072;

  // Q fragments: B-operand of 32x32x16, lane l: col=q (l&31), k=d=ks*16+l5*8+j
  short8 qf[4];
#pragma unroll
  for (int ks = 0; ks < 4; ++ks)
    qf[ks] = *(const short8*)&Qh[(long)qg*64 + ks*16 + l5*8];

  f32x16 o0 = (f32x16)0.0f;   // d 0-31   x q 0-31 (this wave's partial)
  f32x16 o1 = (f32x16)0.0f;   // d 32-63
  float rsum = 0.f;

  // per-lane LDS byte offsets within a tile
  const int koff = l5*2048 + l31*16;   // kf: dblk(l5 part) + key(l31)
  const int voff = l5*1024 + l31*16;   // vf: keyblk(l5 part) + d(l31)
  const int ktmax = qt;

  // prologue: stage tile 0 into buf 0 (4 cp16 per thread: K,V,K,V)
#pragma unroll
  for (int c = 0; c < 2; ++c) {
    int tp = c*512 + tid;
    ASYNC_CP16(Kh + tp*8, &lk[0][tp*8]);
    ASYNC_CP16(Vh + tp*8, &lv[0][tp*8]);
  }

  for (int kt = 0; kt <= ktmax; ++kt) {
    const int cur = kt & 1;
    if (kt < ktmax) {
      const long off = (long)(kt + 1)*8192;
#pragma unroll
      for (int c = 0; c < 2; ++c) {
        int tp = c*512 + tid;
        ASYNC_CP16(Kh + off + tp*8, &lk[cur^1][tp*8]);
        ASYNC_CP16(Vh + off + tp*8, &lv[cur^1][tp*8]);
      }
      asm volatile("s_waitcnt vmcnt(4)" ::: "memory");
    } else {
      asm volatile("s_waitcnt vmcnt(0)" ::: "memory");
    }
    __builtin_amdgcn_s_barrier();

    const char* lkc = (const char*)lk + cur*16384;
    const char* lvc = (const char*)lv + cur*16384;

    // diagonal tile: waves whose whole key-half exceeds their q range skip
    const bool active = !(kt == ktmax && hh*64 > wq*32 + 31);
    if (active) {
      short8 pf[4];   // PV B-fragments, key-slices (hh*4+j)*16..+15
#pragma unroll
      for (int sbl = 0; sbl < 2; ++sbl) {
        // S^T(32 keys x 32 q) = K . Q^T over d=64 (4 k-slices)
        f32x16 sa = (f32x16)0.0f;
#pragma unroll
        for (int ks = 0; ks < 4; ++ks) {
          short8 kf = *(const short8*)(lkc + koff + ks*4096 + (hh*2 + sbl)*512);
          sa = __builtin_amdgcn_mfma_f32_32x32x16_bf16(kf, qf[ks], sa, 0, 0, 0);
        }
        // causal mask (diagonal tile only); key = base + 8g + rr
        if (kt == ktmax) {
          const int kb = kt*128 + hh*64 + sbl*32 + 4*l5;
#pragma unroll
          for (int g = 0; g < 4; ++g)
#pragma unroll
            for (int rr = 0; rr < 4; ++rr)
              if (kb + 8*g + rr > qg) sa[4*g + rr] = -1e30f;
        }
        // p = exp2(s); per-lane l partial; pack to bf16 pairs
        float p[16];
#pragma unroll
        for (int r = 0; r < 16; ++r) p[r] = __builtin_amdgcn_exp2f(sa[r]);
#pragma unroll
        for (int g = 0; g < 4; ++g)
          rsum += (p[4*g] + p[4*g+1]) + (p[4*g+2] + p[4*g+3]);
        u32 cc[4][2];
#pragma unroll
        for (int g = 0; g < 4; ++g) {
          cc[g][0] = cvtpk(p[4*g],   p[4*g+1]);
          cc[g][1] = cvtpk(p[4*g+2], p[4*g+3]);
        }
        // cross-half exchange: one swap fills two output words
        plswap(cc[0][0], cc[1][0]); plswap(cc[0][1], cc[1][1]);
        plswap(cc[2][0], cc[3][0]); plswap(cc[2][1], cc[3][1]);
        u32x4 pw0 = {cc[0][0], cc[0][1], cc[1][0], cc[1][1]};
        u32x4 pw1 = {cc[2][0], cc[2][1], cc[3][0], cc[3][1]};
        pf[sbl*2]     = __builtin_bit_cast(short8, pw0);
        pf[sbl*2 + 1] = __builtin_bit_cast(short8, pw1);
      }
      // PV: o(d x q) += V^T . P over this wave's 64 keys (4 k-slices)
#pragma unroll
      for (int j = 0; j < 4; ++j) {
        const char* vb = lvc + voff + (hh*4 + j)*2048;
        short8 vf0 = *(const short8*)(vb);
        o0 = __builtin_amdgcn_mfma_f32_32x32x16_bf16(vf0, pf[j], o0, 0, 0, 0);
        short8 vf1 = *(const short8*)(vb + 512);
        o1 = __builtin_amdgcn_mfma_f32_32x32x16_bf16(vf1, pf[j], o1, 0, 0, 0);
      }
    }

    asm volatile("" ::: "memory");
    __builtin_amdgcn_s_barrier();
  }

  // ---- epilogue: combine the two key-half partials (waves w and w+4) ----
  __syncthreads();                       // all tile LDS ops done; reuse lk/lv
  float* exf = (float*)&lk[0][0];        // 32 KB: [wq 4][lane 64][32 f32]
  float* rxf = (float*)&lv[0][0];        // [wq 4][lane 64] l-partials
  const int sw = lane & 7;               // 16B-chunk swizzle
  float* xb = exf + wq*2048 + lane*32;

  if (hh == 1) {
#pragma unroll
    for (int c = 0; c < 4; ++c) {
      f32x4 v; v[0]=o0[c*4]; v[1]=o0[c*4+1]; v[2]=o0[c*4+2]; v[3]=o0[c*4+3];
      *(f32x4*)(xb + ((c ^ sw)*4)) = v;
    }
#pragma unroll
    for (int c = 0; c < 4; ++c) {
      f32x4 v; v[0]=o1[c*4]; v[1]=o1[c*4+1]; v[2]=o1[c*4+2]; v[3]=o1[c*4+3];
      *(f32x4*)(xb + (((c+4) ^ sw)*4)) = v;
    }
    rxf[wq*64 + lane] = rsum;
  }
  __syncthreads();
  if (hh == 0) {
    float rt = rsum + rxf[wq*64 + lane];
    rt += __shfl_xor(rt, 32, 64);
    const float inv = 1.0f / rt;
#pragma unroll
    for (int c = 0; c < 4; ++c) {
      f32x4 v = *(const f32x4*)(xb + ((c ^ sw)*4));
      o0[c*4] += v[0]; o0[c*4+1] += v[1]; o0[c*4+2] += v[2]; o0[c*4+3] += v[3];
    }
#pragma unroll
    for (int c = 0; c < 4; ++c) {
      f32x4 v = *(const f32x4*)(xb + (((c+4) ^ sw)*4));
      o1[c*4] += v[0]; o1[c*4+1] += v[1]; o1[c*4+2] += v[2]; o1[c*4+3] += v[3];
    }
    // write bf16 [tok][1024] (merged heads); d = dt*32 + 8g + 4*l5 + rr
    const int b = bh >> 4, h = bh & 15;
    const long tok = (long)b*2048 + qg;
    u16* dst = AO + tok*1024 + h*64;
#pragma unroll
    for (int g = 0; g < 4; ++g) {
      uint2 pkv;
      pkv.x = pk2(o0[4*g]*inv,   o0[4*g+1]*inv);
      pkv.y = pk2(o0[4*g+2]*inv, o0[4*g+3]*inv);
      *(uint2*)(dst + 8*g + 4*l5) = pkv;
    }
#pragma unroll
    for (int g = 0; g < 4; ++g) {
      uint2 pkv;
      pkv.x = pk2(o1[4*g]*inv,   o1[4*g+1]*inv);
      pkv.y = pk2(o1[4*g+2]*inv, o1[4*g+3]*inv);
      *(uint2*)(dst + 32 + 8*g + 4*l5) = pkv;
    }
  }
}

// ---------------------------------------------------------------------------
extern "C" void kernel_launch(void* const* d_in, const int* in_sizes, int n_in,
                              void* d_out, int out_size, void* d_ws, size_t ws_size,
                              hipStream_t stream)
{
  const float* xq  = (const float*)d_in[0];
  const float* xkv = (const float*)d_in[1];
  const float* Wq  = (const float*)d_in[2];
  const float* bq  = (const float*)d_in[3];
  const float* Wk  = (const float*)d_in[4];
  const float* bk  = (const float*)d_in[5];
  const float* Wv  = (const float*)d_in[6];
  const float* bv  = (const float*)d_in[7];
  const float* Wo  = (const float*)d_in[8];
  const float* bo  = (const float*)d_in[9];

  u16* ws    = (u16*)d_ws;
  u16* xq_b  = ws;                    // 8M bf16
  u16* xkv_b = xq_b  + (1l<<23);      // 8M
  u16* wq_b  = xkv_b + (1l<<23);      // 1M
  u16* wk_b  = wq_b  + (1l<<20);
  u16* wv_b  = wk_b  + (1l<<20);
  u16* wo_b  = wv_b  + (1l<<20);
  u16* Qb    = wo_b  + (1l<<20);      // 8M, [bh][n][64], scaled 0.125*log2e
  u16* Kb    = Qb    + (1l<<23);      // 8M, [bh][kt][dblk][key][8]
  u16* Vb    = Kb    + (1l<<23);      // 8M, [bh][kt][keyblk][d][8]
  u16* Ab    = Vb    + (1l<<23);      // 8M, [tok][1024]

  convert_all<<<20480, 256, 0, stream>>>(xq, xkv, Wq, Wk, Wv, Wo, ws);
  gemm_k<0><<<dim3(64,8,3), 256, 0, stream>>>(xq_b, xkv_b, wq_b, wk_b, wv_b,
                                              bq, bk, bv, Qb, Kb, Vb, nullptr);
  attn_k<<<dim3(16,64), 512, 0, stream>>>(Qb, Kb, Vb, Ab);
  gemm_k<1><<<dim3(64,8,1), 256, 0, stream>>>(Ab, nullptr, wo_b, nullptr, nullptr,
                                              bo, nullptr, nullptr,
                                              nullptr, nullptr, nullptr,
                                              (float*)d_out);
}